// Round 1
// baseline (259.861 us; speedup 1.0000x reference)
//
#include <hip/hip_runtime.h>

#define BB 8
#define NN 4096
#define CC 64
#define CENTER (32*64 + 32)
#define GTILE 16
#define MCH 128

// ---------------- compile-time geometry: unique squared radii ----------------
struct Geom {
    short gid[2049];    // d2 -> group id (-1 if d2 never occurs)
    short g2d2[2049];   // group id -> d2
    int ng;
};

constexpr Geom makeGeom() {
    Geom t{};
    bool occ[2049] = {};
    for (int y = 0; y < 64; ++y)
        for (int x = 0; x < 64; ++x) {
            int dy = y - 32, dx = x - 32;
            occ[dy*dy + dx*dx] = true;
        }
    int g = 0;
    for (int i = 0; i <= 2048; ++i) {
        if (occ[i]) { t.gid[i] = (short)g; t.g2d2[g] = (short)i; ++g; }
        else t.gid[i] = (short)-1;
    }
    t.ng = g;
    return t;
}

constexpr int NG = makeGeom().ng;
__constant__ Geom GEOM = makeGeom();

// ---------------- workspace layout (float offsets) ----------------
#define OFF_S    0                       // BB*NN floats: s[b][m]
#define OFF_SMAX (BB*NN)                 // 8 unsigned (monotone-encoded fp32 max)
#define OFF_VP   (BB*NN + 16)            // BB*NN*CC floats: vp[b][m][c]
#define OFF_OG   (OFF_VP + BB*NN*CC)     // BB*NG*CC floats: og[b][g][c]

// ---------------- kernel 1: prep + vp + s + smax ----------------
// grid 128 blocks x 256 threads, one thread per (b,m) row (256 rows/block)
__global__ __launch_bounds__(256) void k_vps(
    const float* __restrict__ x,
    const float* __restrict__ wq, const float* __restrict__ bq,
    const float* __restrict__ wk, const float* __restrict__ bk,
    const float* __restrict__ wv, const float* __restrict__ bv,
    const float* __restrict__ wp,
    float* __restrict__ ws)
{
    __shared__ __align__(16) float wvp_s[CC*CC];  // fused wp@wv, [c][i]
    __shared__ float bvp_s[CC];
    __shared__ float qc_s[CC];
    __shared__ __align__(16) float u_s[CC];
    __shared__ float t_s;

    const int tid  = threadIdx.x;
    const int row0 = blockIdx.x * 256;
    const int b    = row0 >> 12;            // 16 blocks per batch

    // wvp[c][i] = sum_j wp[c][j]*wv[j][i]
    for (int idx = tid; idx < CC*CC; idx += 256) {
        const int c = idx >> 6, i = idx & 63;
        float a = 0.f;
        for (int j = 0; j < CC; ++j) a += wp[c*CC + j] * wv[j*CC + i];
        wvp_s[idx] = a;
    }
    if (tid < CC) {
        float a = 0.f;
        for (int j = 0; j < CC; ++j) a += wp[tid*CC + j] * bv[j];
        bvp_s[tid] = a;
        // central q for this block's batch
        const float* xc = x + ((size_t)b*NN + CENTER)*CC;
        float q = bq[tid];
        for (int i = 0; i < CC; ++i) q += xc[i] * wq[tid*CC + i];
        qc_s[tid] = q;
    }
    __syncthreads();
    if (tid < CC) {
        float a = 0.f;
        for (int c = 0; c < CC; ++c) a += qc_s[c] * wk[c*CC + tid];
        u_s[tid] = a;
    }
    if (tid == 0) {
        float a = 0.f;
        for (int c = 0; c < CC; ++c) a += qc_s[c] * bk[c];
        t_s = a;
    }
    __syncthreads();

    const int row = row0 + tid;
    const float4* x4 = (const float4*)(x + (size_t)row * CC);
    float4 xr[16];
    #pragma unroll
    for (int i = 0; i < 16; ++i) xr[i] = x4[i];

    // s[b][m] = scale * (u . x_row + t)
    const float4* u4 = (const float4*)u_s;
    float sa = t_s;
    #pragma unroll
    for (int i = 0; i < 16; ++i) {
        const float4 uu = u4[i];
        sa += xr[i].x*uu.x + xr[i].y*uu.y + xr[i].z*uu.z + xr[i].w*uu.w;
    }
    sa *= 0.125f;
    ws[OFF_S + row] = sa;

    // per-wave max -> one device atomic per wave (monotone uint encoding)
    float mx = sa;
    #pragma unroll
    for (int off = 32; off > 0; off >>= 1)
        mx = fmaxf(mx, __shfl_xor(mx, off, 64));
    if ((tid & 63) == 0) {
        unsigned u = __float_as_uint(mx);
        unsigned key = (u & 0x80000000u) ? ~u : (u | 0x80000000u);
        atomicMax((unsigned*)(ws + OFF_SMAX) + b, key);
    }

    // vp[b][m][c] = x_row . wvp[c][:] + bvp[c]
    float4* vp4 = (float4*)(ws + OFF_VP) + (size_t)row * 16;
    const float4* wvp4 = (const float4*)wvp_s;
    #pragma unroll 1
    for (int c4 = 0; c4 < 16; ++c4) {
        float ax = bvp_s[c4*4+0], ay = bvp_s[c4*4+1],
              az = bvp_s[c4*4+2], aw = bvp_s[c4*4+3];
        #pragma unroll
        for (int i4 = 0; i4 < 16; ++i4) {
            const float4 xi = xr[i4];
            const float4 wa = wvp4[(c4*4+0)*16 + i4];
            const float4 wb = wvp4[(c4*4+1)*16 + i4];
            const float4 wc = wvp4[(c4*4+2)*16 + i4];
            const float4 wd = wvp4[(c4*4+3)*16 + i4];
            ax += xi.x*wa.x + xi.y*wa.y + xi.z*wa.z + xi.w*wa.w;
            ay += xi.x*wb.x + xi.y*wb.y + xi.z*wb.z + xi.w*wb.w;
            az += xi.x*wc.x + xi.y*wc.y + xi.z*wc.z + xi.w*wc.w;
            aw += xi.x*wd.x + xi.y*wd.y + xi.z*wd.z + xi.w*wd.w;
        }
        vp4[c4] = make_float4(ax, ay, az, aw);
    }
}

// ---------------- kernel 2: grouped softmax-PV ----------------
// grid 8*ceil(NG/16) blocks x 256 threads; block = (batch b, 16 radius-groups)
#define FMA4(A, E, V) do { (A).x += (E)*(V).x; (A).y += (E)*(V).y; \
                           (A).z += (E)*(V).z; (A).w += (E)*(V).w; } while(0)

__global__ __launch_bounds__(256) void k_attn(
    const float* __restrict__ ws_c, float* __restrict__ ws,
    const float* __restrict__ bp)
{
    __shared__ __align__(16) float sd[NN];          // 16 KB: s - smax
    __shared__ __align__(16) float Es[MCH*GTILE];   // 8 KB: exp chunk [mloc][g]
    __shared__ float o_s[GTILE*CC];                 // 4 KB accumulators
    __shared__ float zred[16*GTILE];
    __shared__ float w_s[GTILE];
    __shared__ float Z_s[GTILE];

    const int tid = threadIdx.x;
    const int b   = blockIdx.x & 7;                 // b == XCD round-robin
    const int g0  = (blockIdx.x >> 3) * GTILE;

    unsigned key = ((const unsigned*)(ws_c + OFF_SMAX))[b];
    unsigned su  = (key & 0x80000000u) ? (key ^ 0x80000000u) : ~key;
    const float smax = __uint_as_float(su);

    const float* s_row = ws_c + OFF_S + b*NN;
    for (int i = tid; i < NN; i += 256) sd[i] = s_row[i] - smax;
    for (int i = tid; i < GTILE*CC; i += 256) o_s[i] = 0.f;
    if (tid < GTILE) {
        const int g = g0 + tid;
        float w = 0.f;
        if (g < NG) w = __expf(1.f - sqrtf((float)GEOM.g2d2[g]));
        w_s[tid] = w;
    }
    __syncthreads();

    const int gE = tid & 15;        // staging: this thread's group
    const int mE = tid >> 4;        // staging: m-lane
    const float wg = w_s[gE];
    const int mm = tid >> 4;        // inner: m-lane
    const int c4 = tid & 15;        // inner: float4 column

    float zacc = 0.f;
    float4 acc[GTILE];
    #pragma unroll
    for (int g = 0; g < GTILE; ++g) acc[g] = make_float4(0.f, 0.f, 0.f, 0.f);

    const float4* vp4 = (const float4*)(ws_c + OFF_VP) + (size_t)b*NN*16;
    const float4* E4  = (const float4*)Es;

    for (int ch = 0; ch < NN; ch += MCH) {
        #pragma unroll
        for (int p = 0; p < MCH/16; ++p) {          // stage E (no redundancy)
            const int ml = mE + 16*p;
            const float e = __expf(wg * sd[ch + ml]);
            Es[ml*GTILE + gE] = e;
            zacc += e;
        }
        __syncthreads();
        #pragma unroll 4
        for (int p = 0; p < MCH/16; ++p) {
            const int ml = mm + 16*p;
            const float4 v4 = vp4[(ch + ml)*16 + c4];
            float4 e4;
            e4 = E4[ml*4 + 0];
            FMA4(acc[0],  e4.x, v4); FMA4(acc[1],  e4.y, v4);
            FMA4(acc[2],  e4.z, v4); FMA4(acc[3],  e4.w, v4);
            e4 = E4[ml*4 + 1];
            FMA4(acc[4],  e4.x, v4); FMA4(acc[5],  e4.y, v4);
            FMA4(acc[6],  e4.z, v4); FMA4(acc[7],  e4.w, v4);
            e4 = E4[ml*4 + 2];
            FMA4(acc[8],  e4.x, v4); FMA4(acc[9],  e4.y, v4);
            FMA4(acc[10], e4.z, v4); FMA4(acc[11], e4.w, v4);
            e4 = E4[ml*4 + 3];
            FMA4(acc[12], e4.x, v4); FMA4(acc[13], e4.y, v4);
            FMA4(acc[14], e4.z, v4); FMA4(acc[15], e4.w, v4);
        }
        __syncthreads();
    }

    zred[mE*GTILE + gE] = zacc;
    #pragma unroll
    for (int g = 0; g < GTILE; ++g) {
        atomicAdd(&o_s[g*CC + c4*4 + 0], acc[g].x);
        atomicAdd(&o_s[g*CC + c4*4 + 1], acc[g].y);
        atomicAdd(&o_s[g*CC + c4*4 + 2], acc[g].z);
        atomicAdd(&o_s[g*CC + c4*4 + 3], acc[g].w);
    }
    __syncthreads();
    if (tid < GTILE) {
        float z = 0.f;
        for (int k = 0; k < 16; ++k) z += zred[k*GTILE + tid];
        Z_s[tid] = z;
    }
    __syncthreads();

    float* og = ws + OFF_OG;
    for (int idx = tid; idx < GTILE*CC; idx += 256) {
        const int g = idx >> 6, c = idx & 63;
        if (g0 + g < NG)
            og[((size_t)b*NG + g0 + g)*CC + c] = o_s[idx] / Z_s[g] + bp[c];
    }
}

// ---------------- kernel 3: gather groups -> output ----------------
// grid 2048 x 256, one float4 per thread
__global__ __launch_bounds__(256) void k_out(
    const float* __restrict__ ws, float* __restrict__ out)
{
    const int i4 = blockIdx.x * 256 + threadIdx.x;   // [0, BB*NN*16)
    const int c4 = i4 & 15;
    const int n  = (i4 >> 4) & (NN - 1);
    const int b  = i4 >> 16;
    const int dy = (n >> 6) - 32, dx = (n & 63) - 32;
    const int g  = GEOM.gid[dy*dy + dx*dx];
    const float4* og4 = (const float4*)(ws + OFF_OG);
    ((float4*)out)[i4] = og4[((size_t)b*NG + g)*16 + c4];
}

// ---------------- host ----------------
extern "C" void kernel_launch(void* const* d_in, const int* in_sizes, int n_in,
                              void* d_out, int out_size, void* d_ws, size_t ws_size,
                              hipStream_t stream) {
    const float* x  = (const float*)d_in[0];
    const float* wq = (const float*)d_in[1];
    const float* bq = (const float*)d_in[2];
    const float* wk = (const float*)d_in[3];
    const float* bk = (const float*)d_in[4];
    const float* wv = (const float*)d_in[5];
    const float* bv = (const float*)d_in[6];
    const float* wp = (const float*)d_in[7];
    const float* bp = (const float*)d_in[8];
    float* ws = (float*)d_ws;

    hipMemsetAsync(ws + OFF_SMAX, 0, 8 * sizeof(unsigned), stream);
    k_vps<<<(BB*NN)/256, 256, 0, stream>>>(x, wq, bq, wk, bk, wv, bv, wp, ws);
    constexpr int GT = (NG + GTILE - 1) / GTILE;
    k_attn<<<8*GT, 256, 0, stream>>>(ws, ws, bp);
    k_out<<<2048, 256, 0, stream>>>(ws, (float*)d_out);
}

// Round 2
// 134.690 us; speedup vs baseline: 1.9293x; 1.9293x over previous
//
#include <hip/hip_runtime.h>

#define BB 8
#define NN 4096
#define CC 64
#define CENTER (32*64 + 32)
#define GTILE 16
#define MCH 128
#define MS 16
#define MSL (NN/MS)      // 256 m-values per k_attn block
#define CUT 256          // d2 >= CUT -> far-field group (w ~ 3e-7, softmax uniform to 1e-6)

// ---------------- compile-time geometry ----------------
struct Geom {
    short gid[2049];    // d2 -> group id
    short g2d2[2049];   // near group id -> d2
    int ng;             // number of near groups
};

constexpr Geom makeGeom() {
    Geom t{};
    bool occ[2049] = {};
    for (int y = 0; y < 64; ++y)
        for (int x = 0; x < 64; ++x) {
            int dy = y - 32, dx = x - 32;
            occ[dy*dy + dx*dx] = true;
        }
    int g = 0;
    for (int i = 0; i < CUT; ++i) {
        if (occ[i]) { t.gid[i] = (short)g; t.g2d2[g] = (short)i; ++g; }
        else t.gid[i] = (short)-1;
    }
    t.ng = g;
    for (int i = CUT; i <= 2048; ++i) t.gid[i] = occ[i] ? (short)g : (short)-1;
    return t;
}

constexpr int NGN = makeGeom().ng;                 // near groups (~100)
constexpr int NT  = (NGN + 1 + GTILE - 1) / GTILE; // g-tiles incl. far group
constexpr int GE  = NT * GTILE;                    // padded group count
__constant__ Geom GEOM = makeGeom();

// ---------------- workspace layout (float offsets) ----------------
constexpr int OFF_S    = 0;                        // BB*NN
constexpr int OFF_WVPT = 32768;                    // wvpT[i][c] = (wp@wv)^T, 4096
constexpr int OFF_BVP  = OFF_WVPT + 4096;          // 64
constexpr int OFF_U    = OFF_BVP + 64;             // BB*64
constexpr int OFF_T    = OFF_U + 512;              // 8 (+pad)
constexpr int OFF_VP   = OFF_T + 16;               // BB*NN*CC
constexpr int OFF_SMAX = OFF_VP + BB*NN*CC;        // 8 keys (+pad)
constexpr int OFF_OG   = OFF_SMAX + 16;            // BB*GE*CC accum
constexpr int OFF_Z    = OFF_OG + BB*GE*CC;        // BB*GE accum
constexpr int WS_END   = OFF_Z + BB*GE;

// ---------------- kernel 0: weight prep (tiny) ----------------
__global__ __launch_bounds__(256) void k_prep(
    const float* __restrict__ x,
    const float* __restrict__ wq, const float* __restrict__ bq,
    const float* __restrict__ wk, const float* __restrict__ bk,
    const float* __restrict__ wv, const float* __restrict__ bv,
    const float* __restrict__ wp,
    float* __restrict__ ws)
{
    const int tid = threadIdx.x;
    const int blk = blockIdx.x;
    if (blk < 8) {                       // per-batch: u[b][i], t[b]
        __shared__ float q_s[CC];
        const int b = blk;
        if (tid < CC) {
            const float* xc = x + ((size_t)b*NN + CENTER)*CC;
            float a = bq[tid];
            for (int i = 0; i < CC; ++i) a += xc[i] * wq[tid*CC + i];
            q_s[tid] = a;
        }
        __syncthreads();
        if (tid < CC) {
            float a = 0.f;
            for (int c = 0; c < CC; ++c) a += q_s[c] * wk[c*CC + tid];
            ws[OFF_U + b*CC + tid] = a;
        }
        if (tid == 64) {
            float a = 0.f;
            for (int c = 0; c < CC; ++c) a += q_s[c] * bk[c];
            ws[OFF_T + b] = a;
        }
    } else if (blk < 24) {               // wvpT[i][c] = sum_j wp[c][j]*wv[j][i]
        const int idx = (blk - 8)*256 + tid;
        const int i = idx >> 6, c = idx & 63;
        float a = 0.f;
        for (int j = 0; j < CC; ++j) a += wp[c*CC + j] * wv[j*CC + i];
        ws[OFF_WVPT + idx] = a;
    } else {                             // bvp = wp @ bv
        if (tid < CC) {
            float a = 0.f;
            for (int j = 0; j < CC; ++j) a += wp[tid*CC + j] * bv[j];
            ws[OFF_BVP + tid] = a;
        }
    }
}

// ---------------- kernel 1: vp + s + smax ----------------
// grid 512: block = (rowblk = blockIdx>>2 : 256 rows, cq = blockIdx&3 : 16 c)
// cq in blockIdx keeps all weight indices wave-uniform -> s_load + v_fmac(v,s,v)
__global__ __launch_bounds__(256) void k_vps(
    const float* __restrict__ x, float* __restrict__ ws)
{
    const int tid = threadIdx.x;
    const int cq  = blockIdx.x & 3;
    const int row = (blockIdx.x >> 2)*256 + tid;
    const int b   = blockIdx.x >> 6;          // 64 blocks per batch

    float4 xr[16];
    const float4* x4 = (const float4*)(x + (size_t)row * CC);
    #pragma unroll
    for (int i = 0; i < 16; ++i) xr[i] = x4[i];

    if (cq == 0) {                            // s + per-batch max
        const float* u = ws + OFF_U + b*CC;   // uniform
        float sa = ws[OFF_T + b];
        #pragma unroll
        for (int i4 = 0; i4 < 16; ++i4) {
            sa += xr[i4].x*u[i4*4+0] + xr[i4].y*u[i4*4+1]
                + xr[i4].z*u[i4*4+2] + xr[i4].w*u[i4*4+3];
        }
        sa *= 0.125f;
        ws[OFF_S + row] = sa;
        float mx = sa;
        #pragma unroll
        for (int off = 32; off > 0; off >>= 1)
            mx = fmaxf(mx, __shfl_xor(mx, off, 64));
        if ((tid & 63) == 0) {
            unsigned uu = __float_as_uint(mx);
            unsigned key = (uu & 0x80000000u) ? ~uu : (uu | 0x80000000u);
            atomicMax((unsigned*)(ws + OFF_SMAX) + b, key);
        }
    }

    // vp[row][c0..c0+15] = x_row . wvpT[:, c] + bvp
    const int c0 = cq * 16;                   // uniform
    const float* wvpT = ws + OFF_WVPT;
    float4 acc[4];
    #pragma unroll
    for (int k = 0; k < 4; ++k) {
        acc[k].x = ws[OFF_BVP + c0 + k*4 + 0];
        acc[k].y = ws[OFF_BVP + c0 + k*4 + 1];
        acc[k].z = ws[OFF_BVP + c0 + k*4 + 2];
        acc[k].w = ws[OFF_BVP + c0 + k*4 + 3];
    }
    #pragma unroll
    for (int i = 0; i < 64; ++i) {
        const float xv = ((const float*)xr)[i];
        const float* wr = wvpT + i*CC + c0;   // uniform -> s_load
        #pragma unroll
        for (int k = 0; k < 4; ++k) {
            acc[k].x += xv * wr[k*4+0];
            acc[k].y += xv * wr[k*4+1];
            acc[k].z += xv * wr[k*4+2];
            acc[k].w += xv * wr[k*4+3];
        }
    }
    float4* vp4 = (float4*)(ws + OFF_VP) + (size_t)row*16 + cq*4;
    #pragma unroll
    for (int k = 0; k < 4; ++k) vp4[k] = acc[k];
}

// ---------------- kernel 2: grouped softmax-PV, m-split ----------------
#define FMA4(A, E, V) do { (A).x += (E)*(V).x; (A).y += (E)*(V).y; \
                           (A).z += (E)*(V).z; (A).w += (E)*(V).w; } while(0)

// grid NT*128: blockIdx = gt*128 + ms*8 + b  (b == blockIdx%8 -> XCD locality)
__global__ __launch_bounds__(256) void k_attn(
    const float* __restrict__ ws_c, float* __restrict__ ws)
{
    __shared__ __align__(16) float Es[MCH*GTILE];          // 8 KB
    __shared__ __align__(16) float red[4*GTILE*GTILE*4];   // 16 KB
    __shared__ float zred[4*GTILE];
    __shared__ float w_s[GTILE];

    const int tid = threadIdx.x;
    const int b   = blockIdx.x & 7;
    const int ms  = (blockIdx.x >> 3) & 15;
    const int gt  = blockIdx.x >> 7;
    const int g0  = gt * GTILE;
    const int m0  = ms * MSL;

    unsigned key = ((const unsigned*)(ws_c + OFF_SMAX))[b];
    unsigned su  = (key & 0x80000000u) ? (key ^ 0x80000000u) : ~key;
    const float smax = __uint_as_float(su);

    if (tid < GTILE) {
        const int g = g0 + tid;
        w_s[tid] = (g < NGN) ? __expf(1.f - sqrtf((float)GEOM.g2d2[g])) : 0.f;
    }
    __syncthreads();

    const int gE = tid & 15;
    const int mE = tid >> 4;
    const float wg = w_s[gE];
    const int c4 = tid & 15;

    float zacc = 0.f;
    float4 acc[GTILE];
    #pragma unroll
    for (int g = 0; g < GTILE; ++g) acc[g] = make_float4(0.f, 0.f, 0.f, 0.f);

    const float* s_row = ws_c + OFF_S + b*NN + m0;
    const float4* vp4  = (const float4*)(ws_c + OFF_VP) + ((size_t)b*NN + m0)*16;
    const float4* E4   = (const float4*)Es;

    for (int ch = 0; ch < MSL; ch += MCH) {
        #pragma unroll
        for (int p = 0; p < MCH/16; ++p) {
            const int ml = mE + 16*p;
            const float e = __expf(wg * (s_row[ch + ml] - smax));
            Es[ml*GTILE + gE] = e;
            zacc += e;
        }
        __syncthreads();
        #pragma unroll
        for (int p = 0; p < MCH/16; ++p) {
            const int ml = mE + 16*p;
            const float4 v4 = vp4[(size_t)(ch + ml)*16 + c4];
            float4 e4;
            e4 = E4[ml*4 + 0];
            FMA4(acc[0],  e4.x, v4); FMA4(acc[1],  e4.y, v4);
            FMA4(acc[2],  e4.z, v4); FMA4(acc[3],  e4.w, v4);
            e4 = E4[ml*4 + 1];
            FMA4(acc[4],  e4.x, v4); FMA4(acc[5],  e4.y, v4);
            FMA4(acc[6],  e4.z, v4); FMA4(acc[7],  e4.w, v4);
            e4 = E4[ml*4 + 2];
            FMA4(acc[8],  e4.x, v4); FMA4(acc[9],  e4.y, v4);
            FMA4(acc[10], e4.z, v4); FMA4(acc[11], e4.w, v4);
            e4 = E4[ml*4 + 3];
            FMA4(acc[12], e4.x, v4); FMA4(acc[13], e4.y, v4);
            FMA4(acc[14], e4.z, v4); FMA4(acc[15], e4.w, v4);
        }
        __syncthreads();
    }

    // epilogue: reduce over mE (in-wave butterfly + cross-wave LDS), then global atomics
    const int l = tid & 63;
    const int wv = tid >> 6;
    #pragma unroll
    for (int g = 0; g < GTILE; ++g) {
        acc[g].x += __shfl_xor(acc[g].x, 16, 64);
        acc[g].y += __shfl_xor(acc[g].y, 16, 64);
        acc[g].z += __shfl_xor(acc[g].z, 16, 64);
        acc[g].w += __shfl_xor(acc[g].w, 16, 64);
        acc[g].x += __shfl_xor(acc[g].x, 32, 64);
        acc[g].y += __shfl_xor(acc[g].y, 32, 64);
        acc[g].z += __shfl_xor(acc[g].z, 32, 64);
        acc[g].w += __shfl_xor(acc[g].w, 32, 64);
    }
    zacc += __shfl_xor(zacc, 16, 64);
    zacc += __shfl_xor(zacc, 32, 64);

    float4* red4 = (float4*)red;
    if (l < 16) {
        #pragma unroll
        for (int g = 0; g < GTILE; ++g)
            red4[(wv*GTILE + g)*GTILE + l] = acc[g];
        zred[wv*16 + l] = zacc;
    }
    __syncthreads();

    {
        const int g = tid >> 4, c = tid & 15;
        float4 o0 = red4[(0*GTILE + g)*GTILE + c];
        float4 o1 = red4[(1*GTILE + g)*GTILE + c];
        float4 o2 = red4[(2*GTILE + g)*GTILE + c];
        float4 o3 = red4[(3*GTILE + g)*GTILE + c];
        o0.x += o1.x + o2.x + o3.x;
        o0.y += o1.y + o2.y + o3.y;
        o0.z += o1.z + o2.z + o3.z;
        o0.w += o1.w + o2.w + o3.w;
        float* dst = ws + OFF_OG + ((size_t)(b*GE + g0 + g))*CC + c*4;
        atomicAdd(dst + 0, o0.x);
        atomicAdd(dst + 1, o0.y);
        atomicAdd(dst + 2, o0.z);
        atomicAdd(dst + 3, o0.w);
        if (tid < 16) {
            float Zg = zred[tid] + zred[16 + tid] + zred[32 + tid] + zred[48 + tid];
            atomicAdd(ws + OFF_Z + b*GE + g0 + tid, Zg);
        }
    }
}

// ---------------- kernel 3: finalize + gather ----------------
__global__ __launch_bounds__(256) void k_out(
    const float* __restrict__ ws, const float* __restrict__ bp,
    float* __restrict__ out)
{
    const int i4 = blockIdx.x * 256 + threadIdx.x;   // [0, BB*NN*16)
    const int c4 = i4 & 15;
    const int n  = (i4 >> 4) & (NN - 1);
    const int b  = i4 >> 16;
    const int dy = (n >> 6) - 32, dx = (n & 63) - 32;
    const int g  = GEOM.gid[dy*dy + dx*dx];
    const float Z = ws[OFF_Z + b*GE + g];
    const float rz = 1.0f / Z;
    const float4 o  = ((const float4*)(ws + OFF_OG))[(size_t)(b*GE + g)*16 + c4];
    const float4 bb = ((const float4*)bp)[c4];
    float4 r;
    r.x = o.x * rz + bb.x;
    r.y = o.y * rz + bb.y;
    r.z = o.z * rz + bb.z;
    r.w = o.w * rz + bb.w;
    ((float4*)out)[i4] = r;
}

// ---------------- host ----------------
extern "C" void kernel_launch(void* const* d_in, const int* in_sizes, int n_in,
                              void* d_out, int out_size, void* d_ws, size_t ws_size,
                              hipStream_t stream) {
    const float* x  = (const float*)d_in[0];
    const float* wq = (const float*)d_in[1];
    const float* bq = (const float*)d_in[2];
    const float* wk = (const float*)d_in[3];
    const float* bk = (const float*)d_in[4];
    const float* wv = (const float*)d_in[5];
    const float* bv = (const float*)d_in[6];
    const float* wp = (const float*)d_in[7];
    const float* bp = (const float*)d_in[8];
    float* ws = (float*)d_ws;

    hipMemsetAsync(ws + OFF_SMAX, 0, (size_t)(WS_END - OFF_SMAX)*sizeof(float), stream);
    k_prep<<<25, 256, 0, stream>>>(x, wq, bq, wk, bk, wv, bv, wp, ws);
    k_vps<<<512, 256, 0, stream>>>(x, ws);
    k_attn<<<NT*128, 256, 0, stream>>>(ws, ws);
    k_out<<<2048, 256, 0, stream>>>(ws, bp, (float*)d_out);
}

// Round 3
// 104.339 us; speedup vs baseline: 2.4906x; 1.2909x over previous
//
#include <hip/hip_runtime.h>

#define BB 8
#define NN 4096
#define CC 64
#define CENTER (32*64 + 32)
#define GTILE 16
#define MS 32            // m-split factor
#define MSL (NN/MS)      // 128 m per k_attn block
#define CUT 64           // d2 >= CUT folded into uniform far group (w <= 9.1e-4)

// ---------------- compile-time geometry ----------------
struct Geom {
    short gid[2049];     // d2 -> group id (far -> NGN)
    short g2d2[64];      // near group id -> d2
    int ng;
};

constexpr Geom makeGeom() {
    Geom t{};
    bool occ[2049] = {};
    for (int y = 0; y < 64; ++y)
        for (int x = 0; x < 64; ++x) {
            int dy = y - 32, dx = x - 32;
            occ[dy*dy + dx*dx] = true;
        }
    int g = 0;
    for (int i = 0; i < CUT; ++i) {
        if (occ[i]) { t.gid[i] = (short)g; t.g2d2[g] = (short)i; ++g; }
        else t.gid[i] = (short)-1;
    }
    t.ng = g;
    for (int i = CUT; i <= 2048; ++i) t.gid[i] = occ[i] ? (short)g : (short)-1;
    return t;
}

constexpr int NGN = makeGeom().ng;                 // near groups (~29)
constexpr int NT  = (NGN + 1 + GTILE - 1) / GTILE; // g-tiles incl. far group
constexpr int GE  = NT * GTILE;                    // padded group count (32)
static_assert(NGN + 1 <= GE, "group padding");
static_assert(MS * 8 == 256, "blockIdx decode shift");
__constant__ Geom GEOM = makeGeom();

// ---------------- workspace layout (float offsets) ----------------
// constants region (written by k_prep, read-only after)
constexpr int CST_WVPT = 0;                        // 4096: (wp@wv)^T  [i][c]
constexpr int CST_BVP  = 4096;                     // 64:  wp@bv
constexpr int CST_U    = 4160;                     // BB*64: wk^T q_central
constexpr int CST_T    = 4672;                     // BB
constexpr int CST_SIZE = 4736;

constexpr int OFF_CST  = 0;
constexpr int OFF_S    = CST_SIZE;                 // BB*NN
constexpr int OFF_VP   = OFF_S + BB*NN;            // BB*NN*CC
constexpr int OFF_PART = OFF_VP + BB*NN*CC;        // BB*MS*GE*CC partials
constexpr int OFF_ZP   = OFF_PART + BB*MS*GE*CC;   // BB*MS*GE
constexpr int OFF_OG   = OFF_ZP + BB*MS*GE;        // BB*GE*CC finalized

// ---------------- kernel 0: weight prep (tiny) ----------------
__global__ __launch_bounds__(256) void k_prep(
    const float* __restrict__ x,
    const float* __restrict__ wq, const float* __restrict__ bq,
    const float* __restrict__ wk, const float* __restrict__ bk,
    const float* __restrict__ wv, const float* __restrict__ bv,
    const float* __restrict__ wp,
    float* __restrict__ cst)
{
    const int tid = threadIdx.x;
    const int blk = blockIdx.x;
    if (blk < 8) {                       // per-batch u[b][i], t[b]
        __shared__ float q_s[CC];
        const int b = blk;
        if (tid < CC) {
            const float* xc = x + ((size_t)b*NN + CENTER)*CC;
            float a = bq[tid];
            for (int i = 0; i < CC; ++i) a += xc[i] * wq[tid*CC + i];
            q_s[tid] = a;
        }
        __syncthreads();
        if (tid < CC) {
            float a = 0.f;
            for (int c = 0; c < CC; ++c) a += q_s[c] * wk[c*CC + tid];
            cst[CST_U + b*CC + tid] = a;
        }
        if (tid == 64) {
            float a = 0.f;
            for (int c = 0; c < CC; ++c) a += q_s[c] * bk[c];
            cst[CST_T + b] = a;
        }
    } else if (blk < 24) {               // wvpT[i][c] = sum_j wp[c][j]*wv[j][i]
        const int idx = (blk - 8)*256 + tid;
        const int i = idx >> 6, c = idx & 63;
        float a = 0.f;
        for (int j = 0; j < CC; ++j) a += wp[c*CC + j] * wv[j*CC + i];
        cst[CST_WVPT + idx] = a;
    } else {                             // bvp = wp @ bv
        if (tid < CC) {
            float a = 0.f;
            for (int j = 0; j < CC; ++j) a += wp[tid*CC + j] * bv[j];
            cst[CST_BVP + tid] = a;
        }
    }
}

// ---------------- kernel 1: vp + s ----------------
// grid 512: blockIdx = rowblk*4 + cq; cq (c-quarter) block-uniform -> s_loads
__global__ __launch_bounds__(256) void k_vps(
    const float* __restrict__ x, const float* __restrict__ cst,
    float* __restrict__ s_out, float* __restrict__ vp_out)
{
    const int tid = threadIdx.x;
    const int cq  = blockIdx.x & 3;
    const int row = (blockIdx.x >> 2)*256 + tid;
    const int b   = blockIdx.x >> 6;          // 64 blocks per batch

    float4 xr[16];
    const float4* x4 = (const float4*)(x + (size_t)row * CC);
    #pragma unroll
    for (int i = 0; i < 16; ++i) xr[i] = x4[i];

    if (cq == 0) {                            // s[b][m] (no max-sub: |w*s|<6)
        const float* u = cst + CST_U + b*CC;
        float sa = cst[CST_T + b];
        #pragma unroll
        for (int i4 = 0; i4 < 16; ++i4) {
            sa += xr[i4].x*u[i4*4+0] + xr[i4].y*u[i4*4+1]
                + xr[i4].z*u[i4*4+2] + xr[i4].w*u[i4*4+3];
        }
        s_out[row] = sa * 0.125f;
    }

    const int c0 = cq * 16;                   // uniform
    float4 acc[4];
    #pragma unroll
    for (int k = 0; k < 4; ++k) {
        acc[k].x = cst[CST_BVP + c0 + k*4 + 0];
        acc[k].y = cst[CST_BVP + c0 + k*4 + 1];
        acc[k].z = cst[CST_BVP + c0 + k*4 + 2];
        acc[k].w = cst[CST_BVP + c0 + k*4 + 3];
    }
    #pragma unroll
    for (int i = 0; i < 64; ++i) {
        const float xv = ((const float*)xr)[i];
        const float* wr = cst + CST_WVPT + i*CC + c0;   // uniform -> s_load
        #pragma unroll
        for (int k = 0; k < 4; ++k) {
            acc[k].x += xv * wr[k*4+0];
            acc[k].y += xv * wr[k*4+1];
            acc[k].z += xv * wr[k*4+2];
            acc[k].w += xv * wr[k*4+3];
        }
    }
    float4* vp4 = (float4*)vp_out + (size_t)row*16 + cq*4;
    #pragma unroll
    for (int k = 0; k < 4; ++k) vp4[k] = acc[k];
}

// ---------------- kernel 2: grouped softmax-PV (partials, no atomics) ----------------
#define FMA4(A, E, V) do { (A).x += (E)*(V).x; (A).y += (E)*(V).y; \
                           (A).z += (E)*(V).z; (A).w += (E)*(V).w; } while(0)

// grid NT*MS*8: blockIdx = (gt*MS + ms)*8 + b   (b = XCD round-robin)
__global__ __launch_bounds__(256) void k_attn(
    const float* __restrict__ sA, const float* __restrict__ vpA,
    float* __restrict__ part, float* __restrict__ zpart)
{
    __shared__ __align__(16) float Es[MSL*GTILE];          // 8 KB
    __shared__ __align__(16) float red[4*GTILE*GTILE*4];   // 16 KB
    __shared__ float zred[4*GTILE];
    __shared__ float w_s[GTILE];

    const int tid = threadIdx.x;
    const int b   = blockIdx.x & 7;
    const int ms  = (blockIdx.x >> 3) & (MS - 1);
    const int gt  = blockIdx.x >> 8;
    const int g0  = gt * GTILE;
    const int m0  = ms * MSL;

    if (tid < GTILE) {
        const int g = g0 + tid;
        w_s[tid] = (g < NGN) ? __expf(1.f - sqrtf((float)GEOM.g2d2[g])) : 0.f;
    }
    __syncthreads();

    const int gE = tid & 15;
    const int mE = tid >> 4;
    const float wg = w_s[gE];
    const int c4 = tid & 15;

    float zacc = 0.f;
    float4 acc[GTILE];
    #pragma unroll
    for (int g = 0; g < GTILE; ++g) acc[g] = make_float4(0.f, 0.f, 0.f, 0.f);

    const float* s_row = sA + b*NN + m0;
    const float4* vp4  = (const float4*)vpA + ((size_t)b*NN + m0)*16;
    const float4* E4   = (const float4*)Es;

    #pragma unroll
    for (int p = 0; p < MSL/16; ++p) {          // stage exp(w*s)
        const int ml = mE + 16*p;
        const float e = __expf(wg * s_row[ml]);
        Es[ml*GTILE + gE] = e;
        zacc += e;
    }
    __syncthreads();
    #pragma unroll
    for (int p = 0; p < MSL/16; ++p) {
        const int ml = mE + 16*p;
        const float4 v4 = vp4[(size_t)ml*16 + c4];
        float4 e4;
        e4 = E4[ml*4 + 0];
        FMA4(acc[0],  e4.x, v4); FMA4(acc[1],  e4.y, v4);
        FMA4(acc[2],  e4.z, v4); FMA4(acc[3],  e4.w, v4);
        e4 = E4[ml*4 + 1];
        FMA4(acc[4],  e4.x, v4); FMA4(acc[5],  e4.y, v4);
        FMA4(acc[6],  e4.z, v4); FMA4(acc[7],  e4.w, v4);
        e4 = E4[ml*4 + 2];
        FMA4(acc[8],  e4.x, v4); FMA4(acc[9],  e4.y, v4);
        FMA4(acc[10], e4.z, v4); FMA4(acc[11], e4.w, v4);
        e4 = E4[ml*4 + 3];
        FMA4(acc[12], e4.x, v4); FMA4(acc[13], e4.y, v4);
        FMA4(acc[14], e4.z, v4); FMA4(acc[15], e4.w, v4);
    }
    __syncthreads();

    // reduce over mE: in-wave butterfly, cross-wave via LDS, one partial store
    const int l  = tid & 63;
    const int wv = tid >> 6;
    #pragma unroll
    for (int g = 0; g < GTILE; ++g) {
        acc[g].x += __shfl_xor(acc[g].x, 16, 64);
        acc[g].y += __shfl_xor(acc[g].y, 16, 64);
        acc[g].z += __shfl_xor(acc[g].z, 16, 64);
        acc[g].w += __shfl_xor(acc[g].w, 16, 64);
        acc[g].x += __shfl_xor(acc[g].x, 32, 64);
        acc[g].y += __shfl_xor(acc[g].y, 32, 64);
        acc[g].z += __shfl_xor(acc[g].z, 32, 64);
        acc[g].w += __shfl_xor(acc[g].w, 32, 64);
    }
    zacc += __shfl_xor(zacc, 16, 64);
    zacc += __shfl_xor(zacc, 32, 64);

    float4* red4 = (float4*)red;
    if (l < 16) {
        #pragma unroll
        for (int g = 0; g < GTILE; ++g)
            red4[(wv*GTILE + g)*GTILE + l] = acc[g];
        zred[wv*16 + l] = zacc;
    }
    __syncthreads();

    {
        const int g = tid >> 4, c = tid & 15;
        float4 o0 = red4[(0*GTILE + g)*GTILE + c];
        float4 o1 = red4[(1*GTILE + g)*GTILE + c];
        float4 o2 = red4[(2*GTILE + g)*GTILE + c];
        float4 o3 = red4[(3*GTILE + g)*GTILE + c];
        o0.x += o1.x + o2.x + o3.x;
        o0.y += o1.y + o2.y + o3.y;
        o0.z += o1.z + o2.z + o3.z;
        o0.w += o1.w + o2.w + o3.w;
        ((float4*)part)[(size_t)((b*MS + ms)*GE + g0 + g)*16 + c] = o0;
        if (tid < 16) {
            float Zg = zred[tid] + zred[16+tid] + zred[32+tid] + zred[48+tid];
            zpart[(b*MS + ms)*GE + g0 + tid] = Zg;
        }
    }
}

// ---------------- kernel 3: reduce partials + finalize ----------------
// grid BB*GE*CC/256 = 64 blocks
__global__ __launch_bounds__(256) void k_red(
    const float* __restrict__ part, const float* __restrict__ zpart,
    const float* __restrict__ bp, float* __restrict__ og)
{
    const int idx = blockIdx.x*256 + threadIdx.x;   // [0, BB*GE*CC)
    const int bg  = idx >> 6;                       // b*GE + g
    const int b   = bg / GE, g = bg - b*GE;
    const int c   = idx & 63;
    float a = 0.f, z = 0.f;
    #pragma unroll 8
    for (int ms = 0; ms < MS; ++ms) {
        a += part[(size_t)((b*MS + ms)*GE + g)*CC + c];
        z += zpart[(b*MS + ms)*GE + g];
    }
    og[(size_t)bg*CC + c] = a / z + bp[c];
}

// ---------------- kernel 4: gather ----------------
__global__ __launch_bounds__(256) void k_out(
    const float* __restrict__ og, float* __restrict__ out)
{
    const int i4 = blockIdx.x * 256 + threadIdx.x;   // [0, BB*NN*16)
    const int c4 = i4 & 15;
    const int n  = (i4 >> 4) & (NN - 1);
    const int b  = i4 >> 16;
    const int dy = (n >> 6) - 32, dx = (n & 63) - 32;
    const int g  = GEOM.gid[dy*dy + dx*dx];
    ((float4*)out)[i4] = ((const float4*)og)[(size_t)(b*GE + g)*16 + c4];
}

// ---------------- host ----------------
extern "C" void kernel_launch(void* const* d_in, const int* in_sizes, int n_in,
                              void* d_out, int out_size, void* d_ws, size_t ws_size,
                              hipStream_t stream) {
    const float* x  = (const float*)d_in[0];
    const float* wq = (const float*)d_in[1];
    const float* bq = (const float*)d_in[2];
    const float* wk = (const float*)d_in[3];
    const float* bk = (const float*)d_in[4];
    const float* wv = (const float*)d_in[5];
    const float* bv = (const float*)d_in[6];
    const float* wp = (const float*)d_in[7];
    const float* bp = (const float*)d_in[8];
    float* ws = (float*)d_ws;

    k_prep<<<25, 256, 0, stream>>>(x, wq, bq, wk, bk, wv, bv, wp, ws + OFF_CST);
    k_vps<<<512, 256, 0, stream>>>(x, ws + OFF_CST, ws + OFF_S, ws + OFF_VP);
    k_attn<<<NT*MS*8, 256, 0, stream>>>(ws + OFF_S, ws + OFF_VP,
                                        ws + OFF_PART, ws + OFF_ZP);
    k_red<<<(BB*GE*CC)/256, 256, 0, stream>>>(ws + OFF_PART, ws + OFF_ZP,
                                              bp, ws + OFF_OG);
    k_out<<<2048, 256, 0, stream>>>(ws + OFF_OG, (float*)d_out);
}